// Round 1
// baseline (1789.324 us; speedup 1.0000x reference)
//
#include <hip/hip_runtime.h>
#include <hip/hip_fp16.h>

// Problem constants
#define NQ   2048      // N_LC == N_TE
#define NB   4         // batch
#define DD   256       // feature dim
#define M1   2049      // NQ + dustbin
#define STR  2064      // padded row stride (halfs), multiple of 8
#define SINK_ITERS 100

typedef __attribute__((ext_vector_type(8))) short short8;
typedef __attribute__((ext_vector_type(4))) float floatx4;

__device__ __forceinline__ unsigned short f2bf(float f) {
  unsigned u = __float_as_uint(f);
  u += 0x7FFF + ((u >> 16) & 1);   // round-to-nearest-even
  return (unsigned short)(u >> 16);
}

// ---------------- fp32 -> bf16 convert ----------------
__global__ void k_cvt(const float* __restrict__ src, unsigned short* __restrict__ dst, int n) {
  int i = blockIdx.x * blockDim.x + threadIdx.x;
  if (i < n) dst[i] = f2bf(src[i]);
}

// ---------------- bf16 MFMA GEMM, C = A * B^T (both [rows x K] row-major) ----
// MODE 0: +bias, relu, -> bf16      (MLP layer 1)
// MODE 1: +bias        -> bf16      (MLP layer 2)
// MODE 2: *1/16, clamp, exp -> half (scores -> E)
template<int MODE>
__global__ __launch_bounds__(256, 2)
void k_gemm_bt(const unsigned short* __restrict__ A,
               const unsigned short* __restrict__ Bt,
               void* __restrict__ Out,
               const float* __restrict__ bias,
               int K, long aBatch, long bBatch, long oBatch, int ostride)
{
  __shared__ __align__(16) unsigned short lA[128 * 32];
  __shared__ __align__(16) unsigned short lB[128 * 32];
  const int tid  = threadIdx.x;
  const int lane = tid & 63;
  const int w    = tid >> 6;
  const int wm   = (w >> 1) * 64;
  const int wn   = (w & 1) * 64;
  const long bz  = blockIdx.z;
  const unsigned short* Ab = A  + bz * aBatch + (long)blockIdx.y * 128 * K;
  const unsigned short* Bb = Bt + bz * bBatch + (long)blockIdx.x * 128 * K;

  floatx4 acc[4][4];
  #pragma unroll
  for (int i = 0; i < 4; i++)
    #pragma unroll
    for (int j = 0; j < 4; j++) acc[i][j] = (floatx4){0.f, 0.f, 0.f, 0.f};

  for (int kt = 0; kt < K; kt += 32) {
    __syncthreads();
    #pragma unroll
    for (int s0 = 0; s0 < 512; s0 += 256) {
      int s = s0 + tid;
      int row = s >> 2, part = s & 3;
      ((uint4*)lA)[s] = *(const uint4*)(Ab + (long)row * K + kt + part * 8);
      ((uint4*)lB)[s] = *(const uint4*)(Bb + (long)row * K + kt + part * 8);
    }
    __syncthreads();
    const int kq = (lane >> 4) * 8;   // k sub-offset within BK=32
    const int rl = lane & 15;         // row within 16x16 tile (A: m, B: n)
    short8 af[4], bf[4];
    #pragma unroll
    for (int t = 0; t < 4; t++) {
      af[t] = *(const short8*)(lA + (wm + t * 16 + rl) * 32 + kq);
      bf[t] = *(const short8*)(lB + (wn + t * 16 + rl) * 32 + kq);
    }
    #pragma unroll
    for (int i = 0; i < 4; i++)
      #pragma unroll
      for (int j = 0; j < 4; j++)
        acc[i][j] = __builtin_amdgcn_mfma_f32_16x16x32_bf16(af[i], bf[j], acc[i][j], 0, 0, 0);
  }

  // epilogue — C/D layout: col = lane&15, row = (lane>>4)*4 + reg  [m89/m91 verified]
  const int cl = lane & 15, qd = lane >> 4;
  #pragma unroll
  for (int i = 0; i < 4; i++)
    #pragma unroll
    for (int j = 0; j < 4; j++) {
      const int col = blockIdx.x * 128 + wn + j * 16 + cl;
      const float bcol = (MODE == 2) ? 0.f : bias[col];
      #pragma unroll
      for (int r = 0; r < 4; r++) {
        const long row = (long)blockIdx.y * 128 + wm + i * 16 + qd * 4 + r;
        float v = acc[i][j][r];
        if (MODE == 0) {
          v += bcol; v = v > 0.f ? v : 0.f;
          ((unsigned short*)Out)[bz * oBatch + row * ostride + col] = f2bf(v);
        } else if (MODE == 1) {
          v += bcol;
          ((unsigned short*)Out)[bz * oBatch + row * ostride + col] = f2bf(v);
        } else {
          v *= 0.0625f;                       // 1/sqrt(256)
          v = fminf(fmaxf(v, -15.f), 11.f);   // keep exp(v) inside half range
          ((__half*)Out)[bz * oBatch + row * ostride + col] = __float2half(__expf(v));
        }
      }
    }
}

// ---------------- fill dustbin row/col + zero padding of E -------------------
__global__ void k_fill(__half* __restrict__ E, const float* __restrict__ alphaPtr) {
  const float ea = __expf(*alphaPtr);
  const int idx = blockIdx.x * blockDim.x + threadIdx.x;
  const int n1 = NB * NQ * 16;  // rows 0..2047, cols 2048..2063
  if (idx < n1) {
    int b = idx / (NQ * 16);
    int rr = idx - b * NQ * 16;
    int i = rr >> 4;
    int j = 2048 + (rr & 15);
    E[((long)b * M1 + i) * STR + j] = (j == 2048) ? __float2half(ea) : __float2half(0.f);
  } else {
    int k = idx - n1;             // dustbin row: NB * STR entries
    if (k < NB * STR) {
      int b = k / STR;
      int j = k - b * STR;
      E[((long)b * M1 + 2048) * STR + j] = (j <= 2048) ? __float2half(ea) : __float2half(0.f);
    }
  }
}

// ---------------- init ev = 1 ------------------------------------------------
__global__ void k_init(float* __restrict__ v, int n) {
  int i = blockIdx.x * blockDim.x + threadIdx.x;
  if (i < n) v[i] = 1.0f;
}

// ---------------- Sinkhorn sweep: uout = mu / (Emat . win), one wave per row -
__global__ __launch_bounds__(256)
void k_sweep(const __half* __restrict__ Emat, const float* __restrict__ win,
             float* __restrict__ uout) {
  const int wv   = blockIdx.x * 4 + (threadIdx.x >> 6);  // 2049 blocks * 4 waves = 8196 rows
  const int lane = threadIdx.x & 63;
  const int b   = wv / M1;
  const int row = wv - b * M1;
  const __half* R  = Emat + ((long)b * M1 + row) * STR;
  const float*  wb = win + b * STR;
  float s = 0.f;
  #pragma unroll
  for (int p = 0; p < 4; p++) {
    const int j = p * 512 + lane * 8;
    uint4 hv = *(const uint4*)(R + j);
    const __half2* hp = (const __half2*)&hv;
    float4 wa = *(const float4*)(wb + j);
    float4 wc = *(const float4*)(wb + j + 4);
    float2 f0 = __half22float2(hp[0]);
    float2 f1 = __half22float2(hp[1]);
    float2 f2 = __half22float2(hp[2]);
    float2 f3 = __half22float2(hp[3]);
    s += f0.x * wa.x + f0.y * wa.y + f1.x * wa.z + f1.y * wa.w
       + f2.x * wc.x + f2.y * wc.y + f3.x * wc.z + f3.y * wc.w;
  }
  if (lane == 0) s += __half2float(R[2048]) * wb[2048];   // dustbin column
  #pragma unroll
  for (int off = 32; off > 0; off >>= 1) s += __shfl_down(s, off);
  if (lane == 0) {
    const float mu = (row == 2048) ? 0.5f : (1.0f / 4096.0f);
    uout[b * STR + row] = mu / s;
  }
}

// ---------------- finalize: out = E * eu * ev * 4096 -------------------------
__global__ void k_final(const __half* __restrict__ E, const float* __restrict__ eu,
                        const float* __restrict__ ev, float* __restrict__ out) {
  const int wv = blockIdx.x;      // NB * M1 rows
  const int b = wv / M1;
  const int i = wv - b * M1;
  const __half* R = E + ((long)b * M1 + i) * STR;
  const float ui = eu[b * STR + i] * 4096.f;   // * exp(-norm)
  const float* evb = ev + b * STR;
  float* orow = out + ((long)b * M1 + i) * M1;
  for (int j = threadIdx.x; j < M1; j += blockDim.x)
    orow[j] = __half2float(R[j]) * ui * evb[j];
}

// ---------------- launch -----------------------------------------------------
extern "C" void kernel_launch(void* const* d_in, const int* in_sizes, int n_in,
                              void* d_out, int out_size, void* d_ws, size_t ws_size,
                              hipStream_t stream) {
  const float* x_lc  = (const float*)d_in[0];
  const float* x_te  = (const float*)d_in[1];
  const float* W1_lc = (const float*)d_in[2];
  const float* b1_lc = (const float*)d_in[3];
  const float* W2_lc = (const float*)d_in[4];
  const float* b2_lc = (const float*)d_in[5];
  const float* W1_te = (const float*)d_in[6];
  const float* b1_te = (const float*)d_in[7];
  const float* W2_te = (const float*)d_in[8];
  const float* b2_te = (const float*)d_in[9];
  const float* alpha = (const float*)d_in[10];

  char* ws = (char*)d_ws;
  // byte offsets (all 16-aligned)
  unsigned short* Xlc = (unsigned short*)(ws + 0);          //  4 MB  (8192x256 bf16)
  unsigned short* Xte = (unsigned short*)(ws + 4194304);    //  4 MB
  unsigned short* Wb  = (unsigned short*)(ws + 8388608);    //  0.5 MB (4 x 256x256 bf16)
  unsigned short* H   = (unsigned short*)(ws + 8912896);    //  4 MB  (hidden, reused)
  unsigned short* F1  = (unsigned short*)(ws + 13107200);   //  4 MB
  unsigned short* F2  = (unsigned short*)(ws + 17301504);   //  4 MB
  __half* E  = (__half*)(ws + 21495808);                    // 33.83 MB (4 x 2049 x 2064 half)
  __half* ET = (__half*)(ws + 55328896);                    // 33.83 MB
  float* eu  = (float*)(ws + 89161984);                     // 4 x 2064 f32
  float* ev  = (float*)(ws + 89195008);                     // 4 x 2064 f32

  const int NX = NB * NQ * DD;   // 2097152
  const int NW = DD * DD;        // 65536

  // converts to bf16
  k_cvt<<<(NX + 255) / 256, 256, 0, stream>>>(x_lc, Xlc, NX);
  k_cvt<<<(NX + 255) / 256, 256, 0, stream>>>(x_te, Xte, NX);
  k_cvt<<<(NW + 255) / 256, 256, 0, stream>>>(W1_lc, Wb,           NW);
  k_cvt<<<(NW + 255) / 256, 256, 0, stream>>>(W2_lc, Wb + 65536,   NW);
  k_cvt<<<(NW + 255) / 256, 256, 0, stream>>>(W1_te, Wb + 131072,  NW);
  k_cvt<<<(NW + 255) / 256, 256, 0, stream>>>(W2_te, Wb + 196608,  NW);

  // MLPs (rows flattened over batch: M = 8192, N = 256, K = 256)
  k_gemm_bt<0><<<dim3(2, 64, 1), 256, 0, stream>>>(Xlc, Wb,          H,  b1_lc, DD, 0, 0, 0, DD);
  k_gemm_bt<1><<<dim3(2, 64, 1), 256, 0, stream>>>(H,   Wb + 65536,  F1, b2_lc, DD, 0, 0, 0, DD);
  k_gemm_bt<0><<<dim3(2, 64, 1), 256, 0, stream>>>(Xte, Wb + 131072, H,  b1_te, DD, 0, 0, 0, DD);
  k_gemm_bt<1><<<dim3(2, 64, 1), 256, 0, stream>>>(H,   Wb + 196608, F2, b2_te, DD, 0, 0, 0, DD);

  // scores -> E = exp(S) and ET = exp(S^T), per batch
  const long ab = (long)NQ * DD;        // 524288
  const long ob = (long)M1 * STR;       // 4229136
  k_gemm_bt<2><<<dim3(16, 16, NB), 256, 0, stream>>>(F1, F2, E,  nullptr, DD, ab, ab, ob, STR);
  k_gemm_bt<2><<<dim3(16, 16, NB), 256, 0, stream>>>(F2, F1, ET, nullptr, DD, ab, ab, ob, STR);

  // dustbin row/col + padding
  const int nfill = NB * NQ * 16 + NB * STR;  // 139328
  k_fill<<<(nfill + 255) / 256, 256, 0, stream>>>(E, alpha);
  k_fill<<<(nfill + 255) / 256, 256, 0, stream>>>(ET, alpha);

  // ev = exp(v0) = 1
  k_init<<<(NB * STR + 255) / 256, 256, 0, stream>>>(ev, NB * STR);

  // Sinkhorn, prob domain: eu = mu/(E.ev), ev = nu/(ET.eu)
  for (int it = 0; it < SINK_ITERS; ++it) {
    k_sweep<<<2049, 256, 0, stream>>>(E,  ev, eu);
    k_sweep<<<2049, 256, 0, stream>>>(ET, eu, ev);
  }

  // out = E * eu * ev * (m+n)
  k_final<<<NB * M1, 256, 0, stream>>>(E, eu, ev, (float*)d_out);
}